// Round 16
// baseline (219.892 us; speedup 1.0000x reference)
//
#include <hip/hip_runtime.h>
#include <hip/hip_bf16.h>

#define B_ 2
#define S_ 1536
#define D_ 1024
#define H_ 16
#define DK_ 64
#define KW_ 48                 // S_/32 mask-bit words per row
#define NT_ 24                 // S_/64 key tiles

#define RET_ELEMS 3145728      // f32 elems: [B,S,D]
#define BITPACK_BLOCKS 18432   // B*S*S/256

typedef __attribute__((ext_vector_type(8))) short short8;
typedef __attribute__((ext_vector_type(8))) unsigned short ushort8v;
typedef __attribute__((ext_vector_type(4))) unsigned short ushort4v;
typedef __attribute__((ext_vector_type(4))) float f32x4;

__device__ __forceinline__ unsigned short bf16_rne(float f) {
    return __builtin_bit_cast(unsigned short, __float2bfloat16(f));
}

// ---------------- fused preproc: bitpack + colsum-zero + 7 f32->bf16 converts ----------------
struct CvtJobs {
    const float* src[7];
    unsigned short* dst[7];
};

__global__ __launch_bounds__(256) void preproc_kernel(
    const float* __restrict__ mask1, unsigned int* __restrict__ bits,
    float* __restrict__ colsum, CvtJobs j)
{
    const int blk = blockIdx.x;
    if (blk < BITPACK_BLOCKS) {
        if (blk < 12) colsum[blk * 256 + threadIdx.x] = 0.f;
        const size_t gid = (size_t)blk * 256 + threadIdx.x;
        const float v = mask1[gid];
        const unsigned long long bal = __ballot(v != 0.f);
        const int l = threadIdx.x & 63;
        if (l == 0)       bits[gid >> 5] = (unsigned int)bal;
        else if (l == 32) bits[gid >> 5] = (unsigned int)(bal >> 32);
        return;
    }
    int rb = blk - BITPACK_BLOCKS;     // 0..6655
    int job, base;
    if (rb < 4608) { job = rb / 1536; base = rb % 1536; }     // q,k,v: 1536 blocks each
    else { rb -= 4608; job = 3 + rb / 512; base = rb % 512; } // 4 weights: 512 each
    const size_t i = ((size_t)base * 256 + threadIdx.x) * 8;
    const float* s = j.src[job] + i;
    float4 f0 = *(const float4*)s;
    float4 f1 = *(const float4*)(s + 4);
    ushort8v u;
    u[0]=bf16_rne(f0.x); u[1]=bf16_rne(f0.y); u[2]=bf16_rne(f0.z); u[3]=bf16_rne(f0.w);
    u[4]=bf16_rne(f1.x); u[5]=bf16_rne(f1.y); u[6]=bf16_rne(f1.z); u[7]=bf16_rne(f1.w);
    *(ushort8v*)(j.dst[job] + i) = u;
}

// ---------------- column count from bits: 192 blocks, 96-row partials ----------------
__global__ void colcount_bits_kernel(const unsigned int* __restrict__ bits, float* __restrict__ colsum) {
    const int b     = blockIdx.x / 6;                 // grid.x = 12
    const int chunk = blockIdx.x % 6;
    const int col   = chunk * 256 + threadIdx.x;      // 0..1535
    const int q0    = blockIdx.y * 96;                // grid.y = 16
    const int wword = col >> 5, bit = col & 31;
    const unsigned int* p = bits + ((size_t)b * S_ + q0) * KW_ + wword;
    int s = 0;
    #pragma unroll 8
    for (int q = 0; q < 96; ++q) s += (p[(size_t)q * KW_] >> bit) & 1u;
    atomicAdd(&colsum[b * S_ + col], (float)s);       // integer-valued: exact
}

// ---------------- fac table: per-(b,key) masked ? -1 : 1/colcount ----------------
__global__ void fac_kernel(const int* __restrict__ mask, const float* __restrict__ colsum,
                           float* __restrict__ fac) {
    const int i = blockIdx.x * 256 + threadIdx.x;     // 0..3071
    if (i < B_ * S_) {
        const int km = mask[i];
        const float cnt = colsum[i];
        fac[i] = (km == 0) ? -1.f : ((cnt > 0.f) ? (1.f / cnt) : 0.f);
    }
}

// ---------------- fused QKV projection GEMM: bf16 in, 128x128 tile, BK=64, 512 threads ----------------
struct Proj { const unsigned short* A; const unsigned short* W; const float* bias; unsigned short* C; };

__global__ __launch_bounds__(512) void qkv_gemm_kernel(Proj p0, Proj p1, Proj p2) {
    const int bid = blockIdx.x;
    const int xcd = bid & 7, idx = bid >> 3;          // idx 0..71
    const int zy = xcd * 9 + (idx >> 3);              // 0..71
    const int bx = idx & 7;
    const int z = zy / 24, by = zy % 24;

    const unsigned short* A = z == 0 ? p0.A    : (z == 1 ? p1.A    : p2.A);
    const unsigned short* W = z == 0 ? p0.W    : (z == 1 ? p1.W    : p2.W);
    const float* bias       = z == 0 ? p0.bias : (z == 1 ? p1.bias : p2.bias);
    unsigned short* C       = z == 0 ? p0.C    : (z == 1 ? p1.C    : p2.C);

    __shared__ unsigned short As[128][72];
    __shared__ unsigned short Bs[128][72];
    const int tid = threadIdx.x;
    const int w = tid >> 6, lane = tid & 63;
    const int g = lane >> 4, c = lane & 15;
    const int wm = w >> 2, wn = w & 3;        // 2x4 waves, wave tile 64x32
    const int m0 = by * 128, n0 = bx * 128;
    const int trow = tid >> 2;                // 0..127
    const int tcol = (tid & 3) * 16;          // 0,16,32,48

    f32x4 acc[4][2];
    #pragma unroll
    for (int m = 0; m < 4; ++m)
        #pragma unroll
        for (int n = 0; n < 2; ++n)
            acc[m][n] = f32x4{0.f, 0.f, 0.f, 0.f};

    for (int k0 = 0; k0 < D_; k0 += 64) {
        {
            const unsigned short* ap = A + (size_t)(m0 + trow) * D_ + k0 + tcol;
            *(ushort8v*)&As[trow][tcol]     = *(const ushort8v*)ap;
            *(ushort8v*)&As[trow][tcol + 8] = *(const ushort8v*)(ap + 8);
            const unsigned short* wp = W + (size_t)(n0 + trow) * D_ + k0 + tcol;
            *(ushort8v*)&Bs[trow][tcol]     = *(const ushort8v*)wp;
            *(ushort8v*)&Bs[trow][tcol + 8] = *(const ushort8v*)(wp + 8);
        }
        __syncthreads();
        #pragma unroll
        for (int kk = 0; kk < 2; ++kk) {
            short8 a[4], bb[2];
            #pragma unroll
            for (int m = 0; m < 4; ++m) a[m]  = *(const short8*)&As[wm * 64 + m * 16 + c][kk * 32 + g * 8];
            #pragma unroll
            for (int n = 0; n < 2; ++n) bb[n] = *(const short8*)&Bs[wn * 32 + n * 16 + c][kk * 32 + g * 8];
            #pragma unroll
            for (int m = 0; m < 4; ++m)
                #pragma unroll
                for (int n = 0; n < 2; ++n)
                    acc[m][n] = __builtin_amdgcn_mfma_f32_16x16x32_bf16(a[m], bb[n], acc[m][n], 0, 0, 0);
        }
        __syncthreads();
    }
    #pragma unroll
    for (int n = 0; n < 2; ++n) {
        const int col = n0 + wn * 32 + n * 16 + c;
        const float bval = bias[col];
        #pragma unroll
        for (int m = 0; m < 4; ++m) {
            const int row0 = m0 + wm * 64 + m * 16 + g * 4;
            #pragma unroll
            for (int r = 0; r < 4; ++r)
                C[(size_t)(row0 + r) * D_ + col] = bf16_rne(acc[m][n][r] + bval);
        }
    }
}

// ---------------- final projection: 64x64 tile, 256 threads, bf16 in, f32 out ----------------
__global__ __launch_bounds__(256) void out_gemm_kernel(
    const unsigned short* __restrict__ A, const unsigned short* __restrict__ W,
    const float* __restrict__ bias, float* __restrict__ C)
{
    const int bid = blockIdx.x;
    const int xcd = bid & 7, idx = bid >> 3;          // idx 0..95
    const int yg = xcd * 6 + (idx >> 4);              // 0..47
    const int bx = idx & 15;                          // 0..15

    __shared__ unsigned short As[64][72];
    __shared__ unsigned short Bs[64][72];
    const int tid = threadIdx.x;
    const int w = tid >> 6, lane = tid & 63;
    const int g = lane >> 4, c = lane & 15;
    const int wm = w >> 1, wn = w & 1;        // 2x2 waves, wave tile 32x32
    const int m0 = yg * 64, n0 = bx * 64;
    const int trow = tid >> 2;                // 0..63
    const int tcol = (tid & 3) * 16;

    f32x4 acc[2][2];
    #pragma unroll
    for (int m = 0; m < 2; ++m)
        #pragma unroll
        for (int n = 0; n < 2; ++n)
            acc[m][n] = f32x4{0.f, 0.f, 0.f, 0.f};

    for (int k0 = 0; k0 < D_; k0 += 64) {
        {
            const unsigned short* ap = A + (size_t)(m0 + trow) * D_ + k0 + tcol;
            *(ushort8v*)&As[trow][tcol]     = *(const ushort8v*)ap;
            *(ushort8v*)&As[trow][tcol + 8] = *(const ushort8v*)(ap + 8);
            const unsigned short* wp = W + (size_t)(n0 + trow) * D_ + k0 + tcol;
            *(ushort8v*)&Bs[trow][tcol]     = *(const ushort8v*)wp;
            *(ushort8v*)&Bs[trow][tcol + 8] = *(const ushort8v*)(wp + 8);
        }
        __syncthreads();
        #pragma unroll
        for (int kk = 0; kk < 2; ++kk) {
            short8 a[2], bb[2];
            #pragma unroll
            for (int m = 0; m < 2; ++m) a[m]  = *(const short8*)&As[wm * 32 + m * 16 + c][kk * 32 + g * 8];
            #pragma unroll
            for (int n = 0; n < 2; ++n) bb[n] = *(const short8*)&Bs[wn * 32 + n * 16 + c][kk * 32 + g * 8];
            #pragma unroll
            for (int m = 0; m < 2; ++m)
                #pragma unroll
                for (int n = 0; n < 2; ++n)
                    acc[m][n] = __builtin_amdgcn_mfma_f32_16x16x32_bf16(a[m], bb[n], acc[m][n], 0, 0, 0);
        }
        __syncthreads();
    }
    #pragma unroll
    for (int n = 0; n < 2; ++n) {
        const int col = n0 + wn * 32 + n * 16 + c;
        const float bval = bias[col];
        #pragma unroll
        for (int m = 0; m < 2; ++m) {
            const int row0 = m0 + wm * 32 + m * 16 + g * 4;
            #pragma unroll
            for (int r = 0; r < 4; ++r)
                C[(size_t)(row0 + r) * D_ + col] = acc[m][n][r] + bval;
        }
    }
}

// ---------------- fused attention, S^T layout, QBLK=32 / 128 threads / grid 1536 = 6 blocks/CU ----------------
__global__ __launch_bounds__(128) void attn_kernel(
    const unsigned short* __restrict__ Qb, const unsigned short* __restrict__ Kb,
    const unsigned short* __restrict__ Vb, const float* __restrict__ fac,
    const unsigned int* __restrict__ bits,
    float* __restrict__ scores, unsigned short* __restrict__ X)
{
    // bijective XCD swizzle: 1536 = 8 xcd x 192; each xcd owns 4 (b,h) groups x 48 q-tiles
    const int bid = blockIdx.x;
    const int xcd = bid & 7, idx = bid >> 3;          // idx 0..191
    const int grp = xcd * 4 + idx / 48;               // 0..31
    const int qt  = idx % 48;
    const int h = grp & 15, b = grp >> 4;

    const int tid = threadIdx.x;
    const int w = tid >> 6, lane = tid & 63;
    const int g = lane >> 4, c = lane & 15;

    __shared__ unsigned short VT_lds[2][64][72];   // [buf][dk][k] transposed V tile (18.4 KB)
    __shared__ unsigned short P_lds[2][16][72];    // [wave][q][k] bf16 P (4.6 KB)

    const int qrow0 = qt * 32 + w * 16;
    const unsigned short* qptr = Qb + ((size_t)b * S_ + qrow0 + c) * D_ + h * DK_;
    const short8 qf0 = *(const short8*)(qptr + g * 8);
    const short8 qf1 = *(const short8*)(qptr + 32 + g * 8);

    float mrow = -INFINITY, lrow = 0.f;   // per-lane state for q = qrow0 + c
    f32x4 o[4];
    #pragma unroll
    for (int n = 0; n < 4; ++n) o[n] = f32x4{0.f, 0.f, 0.f, 0.f};

    float* srow = scores + ((((size_t)(b * H_ + h)) * S_ + qrow0 + c) * S_);
    const unsigned int* brow = bits + ((size_t)b * S_ + qrow0 + c) * KW_;
    const float* frow = fac + (size_t)b * S_;

    // V staging: 128 threads; thread (kr, half) stages dk rows half*32..+32 of key column kr
    const int kr = tid & 63, half = tid >> 6;
    const unsigned short* vrow = Vb + ((size_t)b * S_ + kr) * D_ + h * DK_ + half * 32;

    {
        short8 v0 = *(const short8*)vrow;
        short8 v1 = *(const short8*)(vrow + 8);
        short8 v2 = *(const short8*)(vrow + 16);
        short8 v3 = *(const short8*)(vrow + 24);
        #pragma unroll
        for (int j = 0; j < 8; ++j) {
            VT_lds[0][half * 32 + j][kr]      = (unsigned short)v0[j];
            VT_lds[0][half * 32 + 8 + j][kr]  = (unsigned short)v1[j];
            VT_lds[0][half * 32 + 16 + j][kr] = (unsigned short)v2[j];
            VT_lds[0][half * 32 + 24 + j][kr] = (unsigned short)v3[j];
        }
    }
    __syncthreads();   // V tile 0 ready

    for (int kt = 0; kt < NT_; ++kt) {
        const int k0 = kt * 64;
        const int cur = kt & 1;
        const bool have_next = (kt + 1) < NT_;

        short8 nv0, nv1, nv2, nv3;
        if (have_next) {
            const unsigned short* vs = vrow + (size_t)(k0 + 64) * D_;
            nv0 = *(const short8*)vs;
            nv1 = *(const short8*)(vs + 8);
            nv2 = *(const short8*)(vs + 16);
            nv3 = *(const short8*)(vs + 24);
        }

        // ---- S^T = K Q^T ----
        f32x4 sacc[4];
        #pragma unroll
        for (int n = 0; n < 4; ++n) sacc[n] = f32x4{0.f, 0.f, 0.f, 0.f};
        short8 kf0[4], kf1[4];
        #pragma unroll
        for (int n = 0; n < 4; ++n) {
            const unsigned short* kp = Kb + ((size_t)b * S_ + k0 + n * 16 + c) * D_ + h * DK_;
            kf0[n] = *(const short8*)(kp + g * 8);
            kf1[n] = *(const short8*)(kp + 32 + g * 8);
        }
        __builtin_amdgcn_s_setprio(1);
        #pragma unroll
        for (int n = 0; n < 4; ++n) {
            sacc[n] = __builtin_amdgcn_mfma_f32_16x16x32_bf16(kf0[n], qf0, sacc[n], 0, 0, 0);
            sacc[n] = __builtin_amdgcn_mfma_f32_16x16x32_bf16(kf1[n], qf1, sacc[n], 0, 0, 0);
        }
        __builtin_amdgcn_s_setprio(0);

        // ---- factor/mask + scores (nontemporal float4) + tile max ----
        const unsigned int w0 = brow[(k0 >> 5)];
        const unsigned int w1 = brow[(k0 >> 5) + 1];
        float pmax = -INFINITY;
        f32x4 sv[4];
        #pragma unroll
        for (int n = 0; n < 4; ++n) {
            const f32x4 fv = *(const f32x4*)&frow[k0 + n * 16 + g * 4];
            const unsigned int wsel = (n < 2) ? w0 : w1;
            #pragma unroll
            for (int r = 0; r < 4; ++r) {
                const int kl = n * 16 + g * 4 + r;
                const float f = fv[r];
                const float icnt = fmaxf(f, 0.f);
                const float bit = (float)((wsel >> (kl & 31)) & 1u);
                float s = sacc[n][r] * 0.125f * (1.f + bit * icnt);
                s = (f < 0.f) ? -1e9f : s;
                sv[n][r] = s;
                pmax = fmaxf(pmax, s);
            }
            __builtin_nontemporal_store(sv[n], (f32x4*)&srow[k0 + n * 16 + g * 4]);
        }

        // ---- online softmax (per-lane scalar state) ----
        pmax = fmaxf(pmax, __shfl_xor(pmax, 16));
        pmax = fmaxf(pmax, __shfl_xor(pmax, 32));
        const float nm = fmaxf(mrow, pmax);
        const float scq = __expf(mrow - nm);
        mrow = nm;
        lrow *= scq;
        float sc_o[4];
        #pragma unroll
        for (int r = 0; r < 4; ++r) sc_o[r] = __shfl(scq, (lane & 48) | (g * 4 + r));
        #pragma unroll
        for (int n = 0; n < 4; ++n)
            #pragma unroll
            for (int r = 0; r < 4; ++r) o[n][r] *= sc_o[r];

        // ---- P = exp(S - m), vectorized transposed write ----
        #pragma unroll
        for (int n = 0; n < 4; ++n) {
            ushort4v pu;
            #pragma unroll
            for (int r = 0; r < 4; ++r) {
                const float p = __expf(sv[n][r] - mrow);
                lrow += p;
                pu[r] = bf16_rne(p);
            }
            *(ushort4v*)&P_lds[w][c][n * 16 + g * 4] = pu;
        }

        // ---- stage next V tile into other buffer ----
        if (have_next) {
            #pragma unroll
            for (int j = 0; j < 8; ++j) {
                VT_lds[cur ^ 1][half * 32 + j][kr]      = (unsigned short)nv0[j];
                VT_lds[cur ^ 1][half * 32 + 8 + j][kr]  = (unsigned short)nv1[j];
                VT_lds[cur ^ 1][half * 32 + 16 + j][kr] = (unsigned short)nv2[j];
                VT_lds[cur ^ 1][half * 32 + 24 + j][kr] = (unsigned short)nv3[j];
            }
        }

        // ---- O += P V ----
        __builtin_amdgcn_s_setprio(1);
        #pragma unroll
        for (int kk = 0; kk < 2; ++kk) {
            const short8 pa = *(const short8*)&P_lds[w][c][kk * 32 + g * 8];
            #pragma unroll
            for (int n = 0; n < 4; ++n) {
                const short8 vf = *(const short8*)&VT_lds[cur][n * 16 + c][kk * 32 + g * 8];
                o[n] = __builtin_amdgcn_mfma_f32_16x16x32_bf16(pa, vf, o[n], 0, 0, 0);
            }
        }
        __builtin_amdgcn_s_setprio(0);
        __syncthreads();
    }

    // ---- finalize ----
    lrow += __shfl_xor(lrow, 16);
    lrow += __shfl_xor(lrow, 32);
    const float linv = 1.f / lrow;
    float linv_o[4];
    #pragma unroll
    for (int r = 0; r < 4; ++r) linv_o[r] = __shfl(linv, (lane & 48) | (g * 4 + r));
    #pragma unroll
    for (int n = 0; n < 4; ++n)
        #pragma unroll
        for (int r = 0; r < 4; ++r) {
            const size_t idx2 = ((size_t)b * S_ + qrow0 + g * 4 + r) * D_ + h * DK_ + n * 16 + c;
            X[idx2] = bf16_rne(o[n][r] * linv_o[r]);
        }
}

extern "C" void kernel_launch(void* const* d_in, const int* in_sizes, int n_in,
                              void* d_out, int out_size, void* d_ws, size_t ws_size,
                              hipStream_t stream) {
    const float* query = (const float*)d_in[0];
    const float* key   = (const float*)d_in[1];
    const float* value = (const float*)d_in[2];
    const int*   mask  = (const int*)d_in[3];
    const float* mask1 = (const float*)d_in[4];
    const float* Wq = (const float*)d_in[5];
    const float* bq = (const float*)d_in[6];
    const float* Wk = (const float*)d_in[7];
    const float* bk = (const float*)d_in[8];
    const float* Wv = (const float*)d_in[9];
    const float* bv = (const float*)d_in[10];
    const float* Wo = (const float*)d_in[11];
    const float* bo = (const float*)d_in[12];

    float* ret_out    = (float*)d_out;               // f32 [B,S,D]
    float* scores_out = ret_out + RET_ELEMS;         // f32 [B,H,S,S]

    const size_t SZ = (size_t)B_ * S_ * D_;          // 3,145,728
    const size_t WZ = (size_t)D_ * D_;               // 1,048,576
    float* colsum = (float*)d_ws;
    unsigned int* bits = (unsigned int*)((char*)d_ws + 16384);
    unsigned short* Qb  = (unsigned short*)((char*)d_ws + 16384 + 589824);
    unsigned short* Kb  = Qb + SZ;
    unsigned short* Vb  = Kb + SZ;
    unsigned short* Xb  = Vb + SZ;
    unsigned short* qf  = Xb + SZ;
    unsigned short* kf  = qf + SZ;
    unsigned short* vf  = kf + SZ;
    unsigned short* Wqb = vf + SZ;
    unsigned short* Wkb = Wqb + WZ;
    unsigned short* Wvb = Wkb + WZ;
    unsigned short* Wob = Wvb + WZ;
    float* fac = (float*)(Wob + WZ);                 // [B_*S_] f32

    CvtJobs jobs;
    jobs.src[0] = query; jobs.dst[0] = qf;
    jobs.src[1] = key;   jobs.dst[1] = kf;
    jobs.src[2] = value; jobs.dst[2] = vf;
    jobs.src[3] = Wq;    jobs.dst[3] = Wqb;
    jobs.src[4] = Wk;    jobs.dst[4] = Wkb;
    jobs.src[5] = Wv;    jobs.dst[5] = Wvb;
    jobs.src[6] = Wo;    jobs.dst[6] = Wob;

    preproc_kernel<<<BITPACK_BLOCKS + 3 * 1536 + 4 * 512, 256, 0, stream>>>(mask1, bits, colsum, jobs);
    colcount_bits_kernel<<<dim3(12, 16), 256, 0, stream>>>(bits, colsum);
    fac_kernel<<<12, 256, 0, stream>>>(mask, colsum, fac);

    Proj p0{qf, Wqb, bq, Qb}, p1{kf, Wkb, bk, Kb}, p2{vf, Wvb, bv, Vb};
    qkv_gemm_kernel<<<576, 512, 0, stream>>>(p0, p1, p2);

    attn_kernel<<<1536, 128, 0, stream>>>(Qb, Kb, Vb, fac, bits, scores_out, Xb);

    out_gemm_kernel<<<768, 256, 0, stream>>>(Xb, Wob, bo, ret_out);
}

// Round 17
// 201.619 us; speedup vs baseline: 1.0906x; 1.0906x over previous
//
#include <hip/hip_runtime.h>
#include <hip/hip_bf16.h>

#define B_ 2
#define S_ 1536
#define D_ 1024
#define H_ 16
#define DK_ 64
#define KW_ 48                 // S_/32 mask-bit words per row
#define NT_ 24                 // S_/64 key tiles

#define RET_ELEMS 3145728      // f32 elems: [B,S,D]
#define BITPACK_BLOCKS 18432   // B*S*S/256

typedef __attribute__((ext_vector_type(8))) short short8;
typedef __attribute__((ext_vector_type(8))) unsigned short ushort8v;
typedef __attribute__((ext_vector_type(4))) unsigned short ushort4v;
typedef __attribute__((ext_vector_type(4))) float f32x4;

__device__ __forceinline__ unsigned short bf16_rne(float f) {
    return __builtin_bit_cast(unsigned short, __float2bfloat16(f));
}

// ---------------- fused preproc: bitpack + colsum-zero + 7 f32->bf16 converts ----------------
struct CvtJobs {
    const float* src[7];
    unsigned short* dst[7];
};

__global__ __launch_bounds__(256) void preproc_kernel(
    const float* __restrict__ mask1, unsigned int* __restrict__ bits,
    float* __restrict__ colsum, CvtJobs j)
{
    const int blk = blockIdx.x;
    if (blk < BITPACK_BLOCKS) {
        if (blk < 12) colsum[blk * 256 + threadIdx.x] = 0.f;
        const size_t gid = (size_t)blk * 256 + threadIdx.x;
        const float v = mask1[gid];
        const unsigned long long bal = __ballot(v != 0.f);
        const int l = threadIdx.x & 63;
        if (l == 0)       bits[gid >> 5] = (unsigned int)bal;
        else if (l == 32) bits[gid >> 5] = (unsigned int)(bal >> 32);
        return;
    }
    int rb = blk - BITPACK_BLOCKS;     // 0..6655
    int job, base;
    if (rb < 4608) { job = rb / 1536; base = rb % 1536; }     // q,k,v: 1536 blocks each
    else { rb -= 4608; job = 3 + rb / 512; base = rb % 512; } // 4 weights: 512 each
    const size_t i = ((size_t)base * 256 + threadIdx.x) * 8;
    const float* s = j.src[job] + i;
    float4 f0 = *(const float4*)s;
    float4 f1 = *(const float4*)(s + 4);
    ushort8v u;
    u[0]=bf16_rne(f0.x); u[1]=bf16_rne(f0.y); u[2]=bf16_rne(f0.z); u[3]=bf16_rne(f0.w);
    u[4]=bf16_rne(f1.x); u[5]=bf16_rne(f1.y); u[6]=bf16_rne(f1.z); u[7]=bf16_rne(f1.w);
    *(ushort8v*)(j.dst[job] + i) = u;
}

// ---------------- column count from bits: 192 blocks, 96-row partials ----------------
__global__ void colcount_bits_kernel(const unsigned int* __restrict__ bits, float* __restrict__ colsum) {
    const int b     = blockIdx.x / 6;                 // grid.x = 12
    const int chunk = blockIdx.x % 6;
    const int col   = chunk * 256 + threadIdx.x;      // 0..1535
    const int q0    = blockIdx.y * 96;                // grid.y = 16
    const int wword = col >> 5, bit = col & 31;
    const unsigned int* p = bits + ((size_t)b * S_ + q0) * KW_ + wword;
    int s = 0;
    #pragma unroll 8
    for (int q = 0; q < 96; ++q) s += (p[(size_t)q * KW_] >> bit) & 1u;
    atomicAdd(&colsum[b * S_ + col], (float)s);       // integer-valued: exact
}

// ---------------- fused QKV projection GEMM: bf16 in, 128x128 tile, BK=64, 512 threads ----------------
// flat grid 576, XCD-swizzled: xcd=bid&7 owns 9 (z,y) A-panels; panel's 8 N-tiles stay on-XCD
struct Proj { const unsigned short* A; const unsigned short* W; const float* bias; unsigned short* C; };

__global__ __launch_bounds__(512) void qkv_gemm_kernel(Proj p0, Proj p1, Proj p2) {
    const int bid = blockIdx.x;
    const int xcd = bid & 7, idx = bid >> 3;          // idx 0..71
    const int zy = xcd * 9 + (idx >> 3);              // 0..71
    const int bx = idx & 7;
    const int z = zy / 24, by = zy % 24;

    const unsigned short* A = z == 0 ? p0.A    : (z == 1 ? p1.A    : p2.A);
    const unsigned short* W = z == 0 ? p0.W    : (z == 1 ? p1.W    : p2.W);
    const float* bias       = z == 0 ? p0.bias : (z == 1 ? p1.bias : p2.bias);
    unsigned short* C       = z == 0 ? p0.C    : (z == 1 ? p1.C    : p2.C);

    __shared__ unsigned short As[128][72];
    __shared__ unsigned short Bs[128][72];
    const int tid = threadIdx.x;
    const int w = tid >> 6, lane = tid & 63;
    const int g = lane >> 4, c = lane & 15;
    const int wm = w >> 2, wn = w & 3;        // 2x4 waves, wave tile 64x32
    const int m0 = by * 128, n0 = bx * 128;
    const int trow = tid >> 2;                // 0..127
    const int tcol = (tid & 3) * 16;          // 0,16,32,48

    f32x4 acc[4][2];
    #pragma unroll
    for (int m = 0; m < 4; ++m)
        #pragma unroll
        for (int n = 0; n < 2; ++n)
            acc[m][n] = f32x4{0.f, 0.f, 0.f, 0.f};

    for (int k0 = 0; k0 < D_; k0 += 64) {
        {
            const unsigned short* ap = A + (size_t)(m0 + trow) * D_ + k0 + tcol;
            *(ushort8v*)&As[trow][tcol]     = *(const ushort8v*)ap;
            *(ushort8v*)&As[trow][tcol + 8] = *(const ushort8v*)(ap + 8);
            const unsigned short* wp = W + (size_t)(n0 + trow) * D_ + k0 + tcol;
            *(ushort8v*)&Bs[trow][tcol]     = *(const ushort8v*)wp;
            *(ushort8v*)&Bs[trow][tcol + 8] = *(const ushort8v*)(wp + 8);
        }
        __syncthreads();
        #pragma unroll
        for (int kk = 0; kk < 2; ++kk) {
            short8 a[4], bb[2];
            #pragma unroll
            for (int m = 0; m < 4; ++m) a[m]  = *(const short8*)&As[wm * 64 + m * 16 + c][kk * 32 + g * 8];
            #pragma unroll
            for (int n = 0; n < 2; ++n) bb[n] = *(const short8*)&Bs[wn * 32 + n * 16 + c][kk * 32 + g * 8];
            #pragma unroll
            for (int m = 0; m < 4; ++m)
                #pragma unroll
                for (int n = 0; n < 2; ++n)
                    acc[m][n] = __builtin_amdgcn_mfma_f32_16x16x32_bf16(a[m], bb[n], acc[m][n], 0, 0, 0);
        }
        __syncthreads();
    }
    #pragma unroll
    for (int n = 0; n < 2; ++n) {
        const int col = n0 + wn * 32 + n * 16 + c;
        const float bval = bias[col];
        #pragma unroll
        for (int m = 0; m < 4; ++m) {
            const int row0 = m0 + wm * 64 + m * 16 + g * 4;
            #pragma unroll
            for (int r = 0; r < 4; ++r)
                C[(size_t)(row0 + r) * D_ + col] = bf16_rne(acc[m][n][r] + bval);
        }
    }
}

// ---------------- final projection: 64x64 tile, 256 threads, bf16 in, f32 out ----------------
__global__ __launch_bounds__(256) void out_gemm_kernel(
    const unsigned short* __restrict__ A, const unsigned short* __restrict__ W,
    const float* __restrict__ bias, float* __restrict__ C)
{
    const int bid = blockIdx.x;
    const int xcd = bid & 7, idx = bid >> 3;          // idx 0..95
    const int yg = xcd * 6 + (idx >> 4);              // 0..47
    const int bx = idx & 15;                          // 0..15

    __shared__ unsigned short As[64][72];
    __shared__ unsigned short Bs[64][72];
    const int tid = threadIdx.x;
    const int w = tid >> 6, lane = tid & 63;
    const int g = lane >> 4, c = lane & 15;
    const int wm = w >> 1, wn = w & 1;        // 2x2 waves, wave tile 32x32
    const int m0 = yg * 64, n0 = bx * 64;
    const int trow = tid >> 2;                // 0..63
    const int tcol = (tid & 3) * 16;

    f32x4 acc[2][2];
    #pragma unroll
    for (int m = 0; m < 2; ++m)
        #pragma unroll
        for (int n = 0; n < 2; ++n)
            acc[m][n] = f32x4{0.f, 0.f, 0.f, 0.f};

    for (int k0 = 0; k0 < D_; k0 += 64) {
        {
            const unsigned short* ap = A + (size_t)(m0 + trow) * D_ + k0 + tcol;
            *(ushort8v*)&As[trow][tcol]     = *(const ushort8v*)ap;
            *(ushort8v*)&As[trow][tcol + 8] = *(const ushort8v*)(ap + 8);
            const unsigned short* wp = W + (size_t)(n0 + trow) * D_ + k0 + tcol;
            *(ushort8v*)&Bs[trow][tcol]     = *(const ushort8v*)wp;
            *(ushort8v*)&Bs[trow][tcol + 8] = *(const ushort8v*)(wp + 8);
        }
        __syncthreads();
        #pragma unroll
        for (int kk = 0; kk < 2; ++kk) {
            short8 a[2], bb[2];
            #pragma unroll
            for (int m = 0; m < 2; ++m) a[m]  = *(const short8*)&As[wm * 32 + m * 16 + c][kk * 32 + g * 8];
            #pragma unroll
            for (int n = 0; n < 2; ++n) bb[n] = *(const short8*)&Bs[wn * 32 + n * 16 + c][kk * 32 + g * 8];
            #pragma unroll
            for (int m = 0; m < 2; ++m)
                #pragma unroll
                for (int n = 0; n < 2; ++n)
                    acc[m][n] = __builtin_amdgcn_mfma_f32_16x16x32_bf16(a[m], bb[n], acc[m][n], 0, 0, 0);
        }
        __syncthreads();
    }
    #pragma unroll
    for (int n = 0; n < 2; ++n) {
        const int col = n0 + wn * 32 + n * 16 + c;
        const float bval = bias[col];
        #pragma unroll
        for (int m = 0; m < 2; ++m) {
            const int row0 = m0 + wm * 32 + m * 16 + g * 4;
            #pragma unroll
            for (int r = 0; r < 4; ++r)
                C[(size_t)(row0 + r) * D_ + col] = acc[m][n][r] + bval;
        }
    }
}

// ---------------- fused attention, S^T layout, 256 threads (QBLK=64), grid 768 = 3 blocks/CU ----------------
__global__ __launch_bounds__(256) void attn_kernel(
    const unsigned short* __restrict__ Qb, const unsigned short* __restrict__ Kb,
    const unsigned short* __restrict__ Vb, const int* __restrict__ mask,
    const unsigned int* __restrict__ bits, const float* __restrict__ colsum,
    float* __restrict__ scores, unsigned short* __restrict__ X)
{
    // bijective XCD swizzle: 768 = 8 xcd x 96; each xcd owns 4 (b,h) groups x 24 q-tiles
    const int bid = blockIdx.x;
    const int xcd = bid & 7, idx = bid >> 3;          // idx 0..95
    const int grp = xcd * 4 + idx / 24;               // 0..31
    const int qt  = idx % 24;
    const int h = grp & 15, b = grp >> 4;

    const int tid = threadIdx.x;
    const int w = tid >> 6, lane = tid & 63;
    const int g = lane >> 4, c = lane & 15;

    __shared__ unsigned short VT_lds[2][64][72];   // [buf][dk][k] transposed V tile
    __shared__ unsigned short P_lds[4][16][72];    // [wave][q][k] bf16 P
    __shared__ float fac_lds[S_];                  // per-key: masked ? -1 : 1/colcount

    for (int i = tid; i < S_; i += 256) {
        const int km = mask[b * S_ + i];
        const float cnt = colsum[b * S_ + i];
        fac_lds[i] = (km == 0) ? -1.f : ((cnt > 0.f) ? (1.f / cnt) : 0.f);
    }

    const int qrow0 = qt * 64 + w * 16;
    const unsigned short* qptr = Qb + ((size_t)b * S_ + qrow0 + c) * D_ + h * DK_;
    const short8 qf0 = *(const short8*)(qptr + g * 8);
    const short8 qf1 = *(const short8*)(qptr + 32 + g * 8);

    float mrow = -INFINITY, lrow = 0.f;   // per-lane state for q = qrow0 + c
    f32x4 o[4];
    #pragma unroll
    for (int n = 0; n < 4; ++n) o[n] = f32x4{0.f, 0.f, 0.f, 0.f};

    float* srow = scores + ((((size_t)(b * H_ + h)) * S_ + qrow0 + c) * S_);
    const unsigned int* brow = bits + ((size_t)b * S_ + qrow0 + c) * KW_;
    const int kr = tid & 63, half = tid >> 6;
    const unsigned short* vrow = Vb + ((size_t)b * S_ + kr) * D_ + h * DK_ + half * 16;

    {
        short8 v0 = *(const short8*)vrow;
        short8 v1 = *(const short8*)(vrow + 8);
        #pragma unroll
        for (int j = 0; j < 8; ++j) {
            VT_lds[0][half * 16 + j][kr]     = (unsigned short)v0[j];
            VT_lds[0][half * 16 + 8 + j][kr] = (unsigned short)v1[j];
        }
    }
    __syncthreads();   // fac table + V tile 0 ready

    for (int kt = 0; kt < NT_; ++kt) {
        const int k0 = kt * 64;
        const int cur = kt & 1;
        const bool have_next = (kt + 1) < NT_;

        short8 nv0, nv1;
        if (have_next) {
            const unsigned short* vs = vrow + (size_t)(k0 + 64) * D_;
            nv0 = *(const short8*)vs;
            nv1 = *(const short8*)(vs + 8);
        }

        // ---- S^T = K Q^T ----
        f32x4 sacc[4];
        #pragma unroll
        for (int n = 0; n < 4; ++n) sacc[n] = f32x4{0.f, 0.f, 0.f, 0.f};
        short8 kf0[4], kf1[4];
        #pragma unroll
        for (int n = 0; n < 4; ++n) {
            const unsigned short* kp = Kb + ((size_t)b * S_ + k0 + n * 16 + c) * D_ + h * DK_;
            kf0[n] = *(const short8*)(kp + g * 8);
            kf1[n] = *(const short8*)(kp + 32 + g * 8);
        }
        __builtin_amdgcn_s_setprio(1);
        #pragma unroll
        for (int n = 0; n < 4; ++n) {
            sacc[n] = __builtin_amdgcn_mfma_f32_16x16x32_bf16(kf0[n], qf0, sacc[n], 0, 0, 0);
            sacc[n] = __builtin_amdgcn_mfma_f32_16x16x32_bf16(kf1[n], qf1, sacc[n], 0, 0, 0);
        }
        __builtin_amdgcn_s_setprio(0);

        // ---- factor/mask + scores (nontemporal float4) + tile max ----
        const unsigned int w0 = brow[(k0 >> 5)];
        const unsigned int w1 = brow[(k0 >> 5) + 1];
        float pmax = -INFINITY;
        f32x4 sv[4];
        #pragma unroll
        for (int n = 0; n < 4; ++n) {
            const f32x4 fv = *(const f32x4*)&fac_lds[k0 + n * 16 + g * 4];
            const unsigned int wsel = (n < 2) ? w0 : w1;
            #pragma unroll
            for (int r = 0; r < 4; ++r) {
                const int kl = n * 16 + g * 4 + r;
                const float f = fv[r];
                const float icnt = fmaxf(f, 0.f);
                const float bit = (float)((wsel >> (kl & 31)) & 1u);
                float s = sacc[n][r] * 0.125f * (1.f + bit * icnt);
                s = (f < 0.f) ? -1e9f : s;
                sv[n][r] = s;
                pmax = fmaxf(pmax, s);
            }
            __builtin_nontemporal_store(sv[n], (f32x4*)&srow[k0 + n * 16 + g * 4]);
        }

        // ---- online softmax (per-lane scalar state) ----
        pmax = fmaxf(pmax, __shfl_xor(pmax, 16));
        pmax = fmaxf(pmax, __shfl_xor(pmax, 32));
        const float nm = fmaxf(mrow, pmax);
        const float scq = __expf(mrow - nm);
        mrow = nm;
        lrow *= scq;
        float sc_o[4];
        #pragma unroll
        for (int r = 0; r < 4; ++r) sc_o[r] = __shfl(scq, (lane & 48) | (g * 4 + r));
        #pragma unroll
        for (int n = 0; n < 4; ++n)
            #pragma unroll
            for (int r = 0; r < 4; ++r) o[n][r] *= sc_o[r];

        // ---- P = exp(S - m), vectorized transposed write ----
        #pragma unroll
        for (int n = 0; n < 4; ++n) {
            ushort4v pu;
            #pragma unroll
            for (int r = 0; r < 4; ++r) {
                const float p = __expf(sv[n][r] - mrow);
                lrow += p;
                pu[r] = bf16_rne(p);
            }
            *(ushort4v*)&P_lds[w][c][n * 16 + g * 4] = pu;
        }

        // ---- stage next V tile into other buffer ----
        if (have_next) {
            #pragma unroll
            for (int j = 0; j < 8; ++j) {
                VT_lds[cur ^ 1][half * 16 + j][kr]     = (unsigned short)nv0[j];
                VT_lds[cur ^ 1][half * 16 + 8 + j][kr] = (unsigned short)nv1[j];
            }
        }

        // ---- O += P V ----
        __builtin_amdgcn_s_setprio(1);
        #pragma unroll
        for (int kk = 0; kk < 2; ++kk) {
            const short8 pa = *(const short8*)&P_lds[w][c][kk * 32 + g * 8];
            #pragma unroll
            for (int n = 0; n < 4; ++n) {
                const short8 vf = *(const short8*)&VT_lds[cur][n * 16 + c][kk * 32 + g * 8];
                o[n] = __builtin_amdgcn_mfma_f32_16x16x32_bf16(pa, vf, o[n], 0, 0, 0);
            }
        }
        __builtin_amdgcn_s_setprio(0);
        __syncthreads();
    }

    // ---- finalize ----
    lrow += __shfl_xor(lrow, 16);
    lrow += __shfl_xor(lrow, 32);
    const float linv = 1.f / lrow;
    float linv_o[4];
    #pragma unroll
    for (int r = 0; r < 4; ++r) linv_o[r] = __shfl(linv, (lane & 48) | (g * 4 + r));
    #pragma unroll
    for (int n = 0; n < 4; ++n)
        #pragma unroll
        for (int r = 0; r < 4; ++r) {
            const size_t idx2 = ((size_t)b * S_ + qrow0 + g * 4 + r) * D_ + h * DK_ + n * 16 + c;
            X[idx2] = bf16_rne(o[n][r] * linv_o[r]);
        }
}

extern "C" void kernel_launch(void* const* d_in, const int* in_sizes, int n_in,
                              void* d_out, int out_size, void* d_ws, size_t ws_size,
                              hipStream_t stream) {
    const float* query = (const float*)d_in[0];
    const float* key   = (const float*)d_in[1];
    const float* value = (const float*)d_in[2];
    const int*   mask  = (const int*)d_in[3];
    const float* mask1 = (const float*)d_in[4];
    const float* Wq = (const float*)d_in[5];
    const float* bq = (const float*)d_in[6];
    const float* Wk = (const float*)d_in[7];
    const float* bk = (const float*)d_in[8];
    const float* Wv = (const float*)d_in[9];
    const float* bv = (const float*)d_in[10];
    const float* Wo = (const float*)d_in[11];
    const float* bo = (const float*)d_in[12];

    float* ret_out    = (float*)d_out;               // f32 [B,S,D]
    float* scores_out = ret_out + RET_ELEMS;         // f32 [B,H,S,S]

    const size_t SZ = (size_t)B_ * S_ * D_;          // 3,145,728
    const size_t WZ = (size_t)D_ * D_;               // 1,048,576
    float* colsum = (float*)d_ws;
    unsigned int* bits = (unsigned int*)((char*)d_ws + 16384);
    unsigned short* Qb  = (unsigned short*)((char*)d_ws + 16384 + 589824);
    unsigned short* Kb  = Qb + SZ;
    unsigned short* Vb  = Kb + SZ;
    unsigned short* Xb  = Vb + SZ;
    unsigned short* qf  = Xb + SZ;
    unsigned short* kf  = qf + SZ;
    unsigned short* vf  = kf + SZ;
    unsigned short* Wqb = vf + SZ;
    unsigned short* Wkb = Wqb + WZ;
    unsigned short* Wvb = Wkb + WZ;
    unsigned short* Wob = Wvb + WZ;

    CvtJobs jobs;
    jobs.src[0] = query; jobs.dst[0] = qf;
    jobs.src[1] = key;   jobs.dst[1] = kf;
    jobs.src[2] = value; jobs.dst[2] = vf;
    jobs.src[3] = Wq;    jobs.dst[3] = Wqb;
    jobs.src[4] = Wk;    jobs.dst[4] = Wkb;
    jobs.src[5] = Wv;    jobs.dst[5] = Wvb;
    jobs.src[6] = Wo;    jobs.dst[6] = Wob;

    preproc_kernel<<<BITPACK_BLOCKS + 3 * 1536 + 4 * 512, 256, 0, stream>>>(mask1, bits, colsum, jobs);
    colcount_bits_kernel<<<dim3(12, 16), 256, 0, stream>>>(bits, colsum);

    Proj p0{qf, Wqb, bq, Qb}, p1{kf, Wkb, bk, Kb}, p2{vf, Wvb, bv, Vb};
    qkv_gemm_kernel<<<576, 512, 0, stream>>>(p0, p1, p2);

    attn_kernel<<<768, 256, 0, stream>>>(Qb, Kb, Vb, mask, bits, colsum, scores_out, Xb);

    out_gemm_kernel<<<768, 256, 0, stream>>>(Xb, Wob, bo, ret_out);
}

// Round 18
// 188.003 us; speedup vs baseline: 1.1696x; 1.0724x over previous
//
#include <hip/hip_runtime.h>
#include <hip/hip_bf16.h>

#define B_ 2
#define S_ 1536
#define D_ 1024
#define H_ 16
#define DK_ 64
#define KW_ 48                 // S_/32 mask-bit words per row
#define NT_ 24                 // S_/64 key tiles

#define RET_ELEMS 3145728      // f32 elems: [B,S,D]
#define BITPACK_BLOCKS 18432   // B*S*S/256

typedef __attribute__((ext_vector_type(8))) short short8;
typedef __attribute__((ext_vector_type(8))) unsigned short ushort8v;
typedef __attribute__((ext_vector_type(4))) unsigned short ushort4v;
typedef __attribute__((ext_vector_type(4))) float f32x4;

__device__ __forceinline__ unsigned short bf16_rne(float f) {
    return __builtin_bit_cast(unsigned short, __float2bfloat16(f));
}

// ---------------- fused preproc: bitpack + colsum-zero + 7 f32->bf16 converts ----------------
struct CvtJobs {
    const float* src[7];
    unsigned short* dst[7];
};

__global__ __launch_bounds__(256) void preproc_kernel(
    const float* __restrict__ mask1, unsigned int* __restrict__ bits,
    float* __restrict__ colsum, CvtJobs j)
{
    const int blk = blockIdx.x;
    if (blk < BITPACK_BLOCKS) {
        if (blk < 12) colsum[blk * 256 + threadIdx.x] = 0.f;
        const size_t gid = (size_t)blk * 256 + threadIdx.x;
        const float v = mask1[gid];
        const unsigned long long bal = __ballot(v != 0.f);
        const int l = threadIdx.x & 63;
        if (l == 0)       bits[gid >> 5] = (unsigned int)bal;
        else if (l == 32) bits[gid >> 5] = (unsigned int)(bal >> 32);
        return;
    }
    int rb = blk - BITPACK_BLOCKS;     // 0..6655
    int job, base;
    if (rb < 4608) { job = rb / 1536; base = rb % 1536; }     // q,k,v: 1536 blocks each
    else { rb -= 4608; job = 3 + rb / 512; base = rb % 512; } // 4 weights: 512 each
    const size_t i = ((size_t)base * 256 + threadIdx.x) * 8;
    const float* s = j.src[job] + i;
    float4 f0 = *(const float4*)s;
    float4 f1 = *(const float4*)(s + 4);
    ushort8v u;
    u[0]=bf16_rne(f0.x); u[1]=bf16_rne(f0.y); u[2]=bf16_rne(f0.z); u[3]=bf16_rne(f0.w);
    u[4]=bf16_rne(f1.x); u[5]=bf16_rne(f1.y); u[6]=bf16_rne(f1.z); u[7]=bf16_rne(f1.w);
    *(ushort8v*)(j.dst[job] + i) = u;
}

// ---------------- column count from bits: 192 blocks, 96-row partials ----------------
__global__ void colcount_bits_kernel(const unsigned int* __restrict__ bits, float* __restrict__ colsum) {
    const int b     = blockIdx.x / 6;                 // grid.x = 12
    const int chunk = blockIdx.x % 6;
    const int col   = chunk * 256 + threadIdx.x;      // 0..1535
    const int q0    = blockIdx.y * 96;                // grid.y = 16
    const int wword = col >> 5, bit = col & 31;
    const unsigned int* p = bits + ((size_t)b * S_ + q0) * KW_ + wword;
    int s = 0;
    #pragma unroll 8
    for (int q = 0; q < 96; ++q) s += (p[(size_t)q * KW_] >> bit) & 1u;
    atomicAdd(&colsum[b * S_ + col], (float)s);       // integer-valued: exact
}

// ---------------- fused QKV projection GEMM: bf16 in, 128x128 tile, BK=64, 512 threads ----------------
struct Proj { const unsigned short* A; const unsigned short* W; const float* bias; unsigned short* C; };

__global__ __launch_bounds__(512) void qkv_gemm_kernel(Proj p0, Proj p1, Proj p2) {
    const int bid = blockIdx.x;
    const int xcd = bid & 7, idx = bid >> 3;          // idx 0..71
    const int zy = xcd * 9 + (idx >> 3);              // 0..71
    const int bx = idx & 7;
    const int z = zy / 24, by = zy % 24;

    const unsigned short* A = z == 0 ? p0.A    : (z == 1 ? p1.A    : p2.A);
    const unsigned short* W = z == 0 ? p0.W    : (z == 1 ? p1.W    : p2.W);
    const float* bias       = z == 0 ? p0.bias : (z == 1 ? p1.bias : p2.bias);
    unsigned short* C       = z == 0 ? p0.C    : (z == 1 ? p1.C    : p2.C);

    __shared__ unsigned short As[128][72];
    __shared__ unsigned short Bs[128][72];
    const int tid = threadIdx.x;
    const int w = tid >> 6, lane = tid & 63;
    const int g = lane >> 4, c = lane & 15;
    const int wm = w >> 2, wn = w & 3;        // 2x4 waves, wave tile 64x32
    const int m0 = by * 128, n0 = bx * 128;
    const int trow = tid >> 2;                // 0..127
    const int tcol = (tid & 3) * 16;          // 0,16,32,48

    f32x4 acc[4][2];
    #pragma unroll
    for (int m = 0; m < 4; ++m)
        #pragma unroll
        for (int n = 0; n < 2; ++n)
            acc[m][n] = f32x4{0.f, 0.f, 0.f, 0.f};

    for (int k0 = 0; k0 < D_; k0 += 64) {
        {
            const unsigned short* ap = A + (size_t)(m0 + trow) * D_ + k0 + tcol;
            *(ushort8v*)&As[trow][tcol]     = *(const ushort8v*)ap;
            *(ushort8v*)&As[trow][tcol + 8] = *(const ushort8v*)(ap + 8);
            const unsigned short* wp = W + (size_t)(n0 + trow) * D_ + k0 + tcol;
            *(ushort8v*)&Bs[trow][tcol]     = *(const ushort8v*)wp;
            *(ushort8v*)&Bs[trow][tcol + 8] = *(const ushort8v*)(wp + 8);
        }
        __syncthreads();
        #pragma unroll
        for (int kk = 0; kk < 2; ++kk) {
            short8 a[4], bb[2];
            #pragma unroll
            for (int m = 0; m < 4; ++m) a[m]  = *(const short8*)&As[wm * 64 + m * 16 + c][kk * 32 + g * 8];
            #pragma unroll
            for (int n = 0; n < 2; ++n) bb[n] = *(const short8*)&Bs[wn * 32 + n * 16 + c][kk * 32 + g * 8];
            #pragma unroll
            for (int m = 0; m < 4; ++m)
                #pragma unroll
                for (int n = 0; n < 2; ++n)
                    acc[m][n] = __builtin_amdgcn_mfma_f32_16x16x32_bf16(a[m], bb[n], acc[m][n], 0, 0, 0);
        }
        __syncthreads();
    }
    #pragma unroll
    for (int n = 0; n < 2; ++n) {
        const int col = n0 + wn * 32 + n * 16 + c;
        const float bval = bias[col];
        #pragma unroll
        for (int m = 0; m < 4; ++m) {
            const int row0 = m0 + wm * 64 + m * 16 + g * 4;
            #pragma unroll
            for (int r = 0; r < 4; ++r)
                C[(size_t)(row0 + r) * D_ + col] = bf16_rne(acc[m][n][r] + bval);
        }
    }
}

// ---------------- final projection: 64x64 tile, 256 threads, bf16 in, f32 out ----------------
__global__ __launch_bounds__(256) void out_gemm_kernel(
    const unsigned short* __restrict__ A, const unsigned short* __restrict__ W,
    const float* __restrict__ bias, float* __restrict__ C)
{
    const int bid = blockIdx.x;
    const int xcd = bid & 7, idx = bid >> 3;          // idx 0..95
    const int yg = xcd * 6 + (idx >> 4);              // 0..47
    const int bx = idx & 15;                          // 0..15

    __shared__ unsigned short As[64][72];
    __shared__ unsigned short Bs[64][72];
    const int tid = threadIdx.x;
    const int w = tid >> 6, lane = tid & 63;
    const int g = lane >> 4, c = lane & 15;
    const int wm = w >> 1, wn = w & 1;        // 2x2 waves, wave tile 32x32
    const int m0 = yg * 64, n0 = bx * 64;
    const int trow = tid >> 2;                // 0..63
    const int tcol = (tid & 3) * 16;

    f32x4 acc[2][2];
    #pragma unroll
    for (int m = 0; m < 2; ++m)
        #pragma unroll
        for (int n = 0; n < 2; ++n)
            acc[m][n] = f32x4{0.f, 0.f, 0.f, 0.f};

    for (int k0 = 0; k0 < D_; k0 += 64) {
        {
            const unsigned short* ap = A + (size_t)(m0 + trow) * D_ + k0 + tcol;
            *(ushort8v*)&As[trow][tcol]     = *(const ushort8v*)ap;
            *(ushort8v*)&As[trow][tcol + 8] = *(const ushort8v*)(ap + 8);
            const unsigned short* wp = W + (size_t)(n0 + trow) * D_ + k0 + tcol;
            *(ushort8v*)&Bs[trow][tcol]     = *(const ushort8v*)wp;
            *(ushort8v*)&Bs[trow][tcol + 8] = *(const ushort8v*)(wp + 8);
        }
        __syncthreads();
        #pragma unroll
        for (int kk = 0; kk < 2; ++kk) {
            short8 a[2], bb[2];
            #pragma unroll
            for (int m = 0; m < 2; ++m) a[m]  = *(const short8*)&As[wm * 32 + m * 16 + c][kk * 32 + g * 8];
            #pragma unroll
            for (int n = 0; n < 2; ++n) bb[n] = *(const short8*)&Bs[wn * 32 + n * 16 + c][kk * 32 + g * 8];
            #pragma unroll
            for (int m = 0; m < 2; ++m)
                #pragma unroll
                for (int n = 0; n < 2; ++n)
                    acc[m][n] = __builtin_amdgcn_mfma_f32_16x16x32_bf16(a[m], bb[n], acc[m][n], 0, 0, 0);
        }
        __syncthreads();
    }
    #pragma unroll
    for (int n = 0; n < 2; ++n) {
        const int col = n0 + wn * 32 + n * 16 + c;
        const float bval = bias[col];
        #pragma unroll
        for (int m = 0; m < 2; ++m) {
            const int row0 = m0 + wm * 32 + m * 16 + g * 4;
            #pragma unroll
            for (int r = 0; r < 4; ++r)
                C[(size_t)(row0 + r) * D_ + col] = acc[m][n][r] + bval;
        }
    }
}

// ---------------- fused attention, S^T layout, LDS-staged coalesced score stores ----------------
__global__ __launch_bounds__(256) void attn_kernel(
    const unsigned short* __restrict__ Qb, const unsigned short* __restrict__ Kb,
    const unsigned short* __restrict__ Vb, const int* __restrict__ mask,
    const unsigned int* __restrict__ bits, const float* __restrict__ colsum,
    float* __restrict__ scores, unsigned short* __restrict__ X)
{
    // bijective XCD swizzle: 768 = 8 xcd x 96; each xcd owns 4 (b,h) groups x 24 q-tiles
    const int bid = blockIdx.x;
    const int xcd = bid & 7, idx = bid >> 3;          // idx 0..95
    const int grp = xcd * 4 + idx / 24;               // 0..31
    const int qt  = idx % 24;
    const int h = grp & 15, b = grp >> 4;

    const int tid = threadIdx.x;
    const int w = tid >> 6, lane = tid & 63;
    const int g = lane >> 4, c = lane & 15;

    __shared__ unsigned short VT_lds[2][64][72];   // [buf][dk][k] transposed V tile (18.4 KB)
    __shared__ unsigned short P_lds[4][16][72];    // [wave][q][k] bf16 P (9.2 KB)
    __shared__ float SC_lds[4][16][72];            // [wave][q][k] f32 score stage (18.4 KB)
    __shared__ float fac_lds[S_];                  // per-key: masked ? -1 : 1/colcount (6 KB)

    for (int i = tid; i < S_; i += 256) {
        const int km = mask[b * S_ + i];
        const float cnt = colsum[b * S_ + i];
        fac_lds[i] = (km == 0) ? -1.f : ((cnt > 0.f) ? (1.f / cnt) : 0.f);
    }

    const int qrow0 = qt * 64 + w * 16;
    const unsigned short* qptr = Qb + ((size_t)b * S_ + qrow0 + c) * D_ + h * DK_;
    const short8 qf0 = *(const short8*)(qptr + g * 8);
    const short8 qf1 = *(const short8*)(qptr + 32 + g * 8);

    float mrow = -INFINITY, lrow = 0.f;   // per-lane state for q = qrow0 + c
    f32x4 o[4];
    #pragma unroll
    for (int n = 0; n < 4; ++n) o[n] = f32x4{0.f, 0.f, 0.f, 0.f};

    float* sblk = scores + (((size_t)(b * H_ + h)) * S_ + qrow0) * S_;   // wave row-block base
    const unsigned int* brow = bits + ((size_t)b * S_ + qrow0 + c) * KW_;
    const int kr = tid & 63, half = tid >> 6;
    const unsigned short* vrow = Vb + ((size_t)b * S_ + kr) * D_ + h * DK_ + half * 16;
    // coalesced-store lane mapping: 16 consecutive lanes cover one row's 256 B
    const int srr = lane >> 4;            // row offset within 4-row group
    const int scc = (lane & 15) * 4;      // f32 col within 64

    {
        short8 v0 = *(const short8*)vrow;
        short8 v1 = *(const short8*)(vrow + 8);
        #pragma unroll
        for (int j = 0; j < 8; ++j) {
            VT_lds[0][half * 16 + j][kr]     = (unsigned short)v0[j];
            VT_lds[0][half * 16 + 8 + j][kr] = (unsigned short)v1[j];
        }
    }
    __syncthreads();   // fac table + V tile 0 ready

    for (int kt = 0; kt < NT_; ++kt) {
        const int k0 = kt * 64;
        const int cur = kt & 1;
        const bool have_next = (kt + 1) < NT_;

        short8 nv0, nv1;
        if (have_next) {
            const unsigned short* vs = vrow + (size_t)(k0 + 64) * D_;
            nv0 = *(const short8*)vs;
            nv1 = *(const short8*)(vs + 8);
        }

        // ---- S^T = K Q^T ----
        f32x4 sacc[4];
        #pragma unroll
        for (int n = 0; n < 4; ++n) sacc[n] = f32x4{0.f, 0.f, 0.f, 0.f};
        short8 kf0[4], kf1[4];
        #pragma unroll
        for (int n = 0; n < 4; ++n) {
            const unsigned short* kp = Kb + ((size_t)b * S_ + k0 + n * 16 + c) * D_ + h * DK_;
            kf0[n] = *(const short8*)(kp + g * 8);
            kf1[n] = *(const short8*)(kp + 32 + g * 8);
        }
        __builtin_amdgcn_s_setprio(1);
        #pragma unroll
        for (int n = 0; n < 4; ++n) {
            sacc[n] = __builtin_amdgcn_mfma_f32_16x16x32_bf16(kf0[n], qf0, sacc[n], 0, 0, 0);
            sacc[n] = __builtin_amdgcn_mfma_f32_16x16x32_bf16(kf1[n], qf1, sacc[n], 0, 0, 0);
        }
        __builtin_amdgcn_s_setprio(0);

        // ---- factor/mask + tile max; stage scores in LDS (wave-private) ----
        const unsigned int w0 = brow[(k0 >> 5)];
        const unsigned int w1 = brow[(k0 >> 5) + 1];
        float pmax = -INFINITY;
        f32x4 sv[4];
        #pragma unroll
        for (int n = 0; n < 4; ++n) {
            const f32x4 fv = *(const f32x4*)&fac_lds[k0 + n * 16 + g * 4];
            const unsigned int wsel = (n < 2) ? w0 : w1;
            #pragma unroll
            for (int r = 0; r < 4; ++r) {
                const int kl = n * 16 + g * 4 + r;
                const float f = fv[r];
                const float icnt = fmaxf(f, 0.f);
                const float bit = (float)((wsel >> (kl & 31)) & 1u);
                float s = sacc[n][r] * 0.125f * (1.f + bit * icnt);
                s = (f < 0.f) ? -1e9f : s;
                sv[n][r] = s;
                pmax = fmaxf(pmax, s);
            }
            *(f32x4*)&SC_lds[w][c][n * 16 + g * 4] = sv[n];
        }
        // ---- coalesced score write: 4 stores, 16 lanes = one 256-B row each ----
        #pragma unroll
        for (int i = 0; i < 4; ++i) {
            const int rr = i * 4 + srr;
            const f32x4 v = *(const f32x4*)&SC_lds[w][rr][scc];
            __builtin_nontemporal_store(v, (f32x4*)&sblk[(size_t)rr * S_ + k0 + scc]);
        }

        // ---- online softmax (per-lane scalar state) ----
        pmax = fmaxf(pmax, __shfl_xor(pmax, 16));
        pmax = fmaxf(pmax, __shfl_xor(pmax, 32));
        const float nm = fmaxf(mrow, pmax);
        const float scq = __expf(mrow - nm);
        mrow = nm;
        lrow *= scq;
        float sc_o[4];
        #pragma unroll
        for (int r = 0; r < 4; ++r) sc_o[r] = __shfl(scq, (lane & 48) | (g * 4 + r));
        #pragma unroll
        for (int n = 0; n < 4; ++n)
            #pragma unroll
            for (int r = 0; r < 4; ++r) o[n][r] *= sc_o[r];

        // ---- P = exp(S - m), vectorized transposed write ----
        #pragma unroll
        for (int n = 0; n < 4; ++n) {
            ushort4v pu;
            #pragma unroll
            for (int r = 0; r < 4; ++r) {
                const float p = __expf(sv[n][r] - mrow);
                lrow += p;
                pu[r] = bf16_rne(p);
            }
            *(ushort4v*)&P_lds[w][c][n * 16 + g * 4] = pu;
        }

        // ---- stage next V tile into other buffer ----
        if (have_next) {
            #pragma unroll
            for (int j = 0; j < 8; ++j) {
                VT_lds[cur ^ 1][half * 16 + j][kr]     = (unsigned short)nv0[j];
                VT_lds[cur ^ 1][half * 16 + 8 + j][kr] = (unsigned short)nv1[j];
            }
        }

        // ---- O += P V ----
        __builtin_amdgcn_s_setprio(1);
        #pragma unroll
        for (int kk = 0; kk < 2; ++kk) {
            const short8 pa = *(const short8*)&P_lds[w][c][kk * 32 + g * 8];
            #pragma unroll
            for (int n = 0; n < 4; ++n) {
                const short8 vf = *(const short8*)&VT_lds[cur][n * 16 + c][kk * 32 + g * 8];
                o[n] = __builtin_amdgcn_mfma_f32_16x16x32_bf16(pa, vf, o[n], 0, 0, 0);
            }
        }
        __builtin_amdgcn_s_setprio(0);
        __syncthreads();
    }

    // ---- finalize ----
    lrow += __shfl_xor(lrow, 16);
    lrow += __shfl_xor(lrow, 32);
    const float linv = 1.f / lrow;
    float linv_o[4];
    #pragma unroll
    for (int r = 0; r < 4; ++r) linv_o[r] = __shfl(linv, (lane & 48) | (g * 4 + r));
    #pragma unroll
    for (int n = 0; n < 4; ++n)
        #pragma unroll
        for (int r = 0; r < 4; ++r) {
            const size_t idx2 = ((size_t)b * S_ + qrow0 + g * 4 + r) * D_ + h * DK_ + n * 16 + c;
            X[idx2] = bf16_rne(o[n][r] * linv_o[r]);
        }
}

extern "C" void kernel_launch(void* const* d_in, const int* in_sizes, int n_in,
                              void* d_out, int out_size, void* d_ws, size_t ws_size,
                              hipStream_t stream) {
    const float* query = (const float*)d_in[0];
    const float* key   = (const float*)d_in[1];
    const float* value = (const float*)d_in[2];
    const int*   mask  = (const int*)d_in[3];
    const float* mask1 = (const float*)d_in[4];
    const float* Wq = (const float*)d_in[5];
    const float* bq = (const float*)d_in[6];
    const float* Wk = (const float*)d_in[7];
    const float* bk = (const float*)d_in[8];
    const float* Wv = (const float*)d_in[9];
    const float* bv = (const float*)d_in[10];
    const float* Wo = (const float*)d_in[11];
    const float* bo = (const float*)d_in[12];

    float* ret_out    = (float*)d_out;               // f32 [B,S,D]
    float* scores_out = ret_out + RET_ELEMS;         // f32 [B,H,S,S]

    const size_t SZ = (size_t)B_ * S_ * D_;          // 3,145,728
    const size_t WZ = (size_t)D_ * D_;               // 1,048,576
    float* colsum = (float*)d_ws;
    unsigned int* bits = (unsigned int*)((char*)d_ws + 16384);
    unsigned short* Qb  = (unsigned short*)((char*)d_ws + 16384 + 589824);
    unsigned short* Kb  = Qb + SZ;
    unsigned short* Vb  = Kb + SZ;
    unsigned short* Xb  = Vb + SZ;
    unsigned short* qf  = Xb + SZ;
    unsigned short* kf  = qf + SZ;
    unsigned short* vf  = kf + SZ;
    unsigned short* Wqb = vf + SZ;
    unsigned short* Wkb = Wqb + WZ;
    unsigned short* Wvb = Wkb + WZ;
    unsigned short* Wob = Wvb + WZ;

    CvtJobs jobs;
    jobs.src[0] = query; jobs.dst[0] = qf;
    jobs.src[1] = key;   jobs.dst[1] = kf;
    jobs.src[2] = value; jobs.dst[2] = vf;
    jobs.src[3] = Wq;    jobs.dst[3] = Wqb;
    jobs.src[4] = Wk;    jobs.dst[4] = Wkb;
    jobs.src[5] = Wv;    jobs.dst[5] = Wvb;
    jobs.src[6] = Wo;    jobs.dst[6] = Wob;

    preproc_kernel<<<BITPACK_BLOCKS + 3 * 1536 + 4 * 512, 256, 0, stream>>>(mask1, bits, colsum, jobs);
    colcount_bits_kernel<<<dim3(12, 16), 256, 0, stream>>>(bits, colsum);

    Proj p0{qf, Wqb, bq, Qb}, p1{kf, Wkb, bk, Kb}, p2{vf, Wvb, bv, Vb};
    qkv_gemm_kernel<<<576, 512, 0, stream>>>(p0, p1, p2);

    attn_kernel<<<768, 256, 0, stream>>>(Qb, Kb, Vb, mask, bits, colsum, scores_out, Xb);

    out_gemm_kernel<<<768, 256, 0, stream>>>(Xb, Wob, bo, ret_out);
}